// Round 9
// baseline (534.617 us; speedup 1.0000x reference)
//
#include <hip/hip_runtime.h>

#define T_STEPS 128
#define B_SIZE  32768
#define F_DIM   8
#define H_DIM   64

#define BLOCK_THREADS 128                 // 2 waves = one 16-sample team
#define GRID_BLOCKS   (B_SIZE / 16)       // 2048 blocks -> 4096 waves = 4/SIMD

typedef float f32x4 __attribute__((ext_vector_type(4)));
typedef short bfrag __attribute__((ext_vector_type(8)));   // 8 bf16 (4 VGPRs)
typedef unsigned int u32x4 __attribute__((ext_vector_type(4)));

#define MFMA16(A, B, C) __builtin_amdgcn_mfma_f32_16x16x32_bf16((A), (B), (C), 0, 0, 0)

// Barrier that drains ONLY LDS ops: keeps x-prefetch global loads in flight
// across the per-step exchange (__syncthreads would s_waitcnt vmcnt(0) and put
// HBM latency on every step's critical path).
#define LDS_BARRIER() asm volatile("s_waitcnt lgkmcnt(0)\n\ts_barrier" ::: "memory")

__device__ __forceinline__ short f2bf(float f) { return __builtin_bit_cast(short, (__bf16)f); }
__device__ __forceinline__ float4 ld4(const void* p) { return *(const float4*)p; }

constexpr float S1 = 1.4426950408889634f;  // log2(e)   -> folded into r,z weights
constexpr float S2 = 2.f * S1;             // 2*log2(e) -> folded into n weights

// Layout (verified rounds 2-8):
//  A/B frag elem e -> k = 32*kt + 16*(e>>2) + 4*g + (e&3); A row / B col = lane&15
//  C/D: col = lane&15 (sample), row = 4*g + reg (tile tt covers rows 16*tt..16*tt+15)
// Team split: wave w owns h-units [32w, 32w+32) == B k-tile kt=w; exchange via LDS.
//
// Allocator cap law (R2-R8): VGPR cap = 512/(2*min_waves); alloc = min(demand, cap).
// This structure's demand ~110-125: min_waves=2 -> cap 128 >= demand -> NO spill,
// and floor(512/demand) = 4 waves/SIMD actually resident (grid provides exactly 4).
// min_waves=3 (R7) capped at 84 -> 47 MB scratch spill on the critical path.

__global__ void __launch_bounds__(BLOCK_THREADS, 2)
seq2seq_r9_kernel(const float* __restrict__ inputs, const float* __restrict__ target,
                  const float* __restrict__ eWih, const float* __restrict__ eWhh,
                  const float* __restrict__ ebih, const float* __restrict__ ebhh,
                  const float* __restrict__ dWih, const float* __restrict__ dWhh,
                  const float* __restrict__ dbih, const float* __restrict__ dbhh,
                  const float* __restrict__ oW, const float* __restrict__ ob,
                  float* __restrict__ out)
{
    __shared__ u32x4 sEx[2][2][64];   // [parity][wave][lane] = 4 KB

    const int tid  = threadIdx.x;
    const int lane = tid & 63;
    const int w    = tid >> 6;        // wave id in team (0/1)
    const int c    = lane & 15;       // sample col
    const int g    = lane >> 4;       // lane group

    bfrag wr[2][2], wz[2][2], whn[2][2];   // [tl][j]: j=0 -> own kt(=w), j=1 -> partner
    bfrag xr[2], xz[2], xnw[2];            // x-ktile A-frags (k<8 = Wih, k==8 = bias row)
    f32x4 bhn[2];                          // bhh n-rows (scaled) -> acc-init for aHN

    auto load_phase = [&](const float* __restrict__ Wih, const float* __restrict__ Whh,
                          const float* __restrict__ bih, const float* __restrict__ bhh) {
#pragma unroll
        for (int tl = 0; tl < 2; ++tl) {
            const int tt = 2 * w + tl;
            const int rowR = 16 * tt + c, rowZ = rowR + 64, rowN = rowR + 128;
#pragma unroll
            for (int j = 0; j < 2; ++j) {
                const int kt = (j == 0) ? w : 1 - w;
                bfrag fr, fz, fn;
#pragma unroll
                for (int e = 0; e < 8; ++e) {
                    const int k = 32 * kt + 16 * (e >> 2) + 4 * g + (e & 3);
                    fr[e] = f2bf(Whh[rowR * H_DIM + k] * S1);
                    fz[e] = f2bf(Whh[rowZ * H_DIM + k] * S1);
                    fn[e] = f2bf(Whh[rowN * H_DIM + k] * S2);
                }
                wr[tl][j] = fr; wz[tl][j] = fz; whn[tl][j] = fn;
            }
            bfrag axr, axz, axn;
#pragma unroll
            for (int e = 0; e < 8; ++e) {
                const int k = 16 * (e >> 2) + 4 * g + (e & 3);
                float vr = 0.f, vz = 0.f, vn = 0.f;
                if (k < F_DIM) {
                    vr = Wih[rowR * F_DIM + k]; vz = Wih[rowZ * F_DIM + k]; vn = Wih[rowN * F_DIM + k];
                } else if (k == F_DIM) {
                    vr = bih[rowR] + bhh[rowR]; vz = bih[rowZ] + bhh[rowZ]; vn = bih[rowN];
                }
                axr[e] = f2bf(vr * S1); axz[e] = f2bf(vz * S1); axn[e] = f2bf(vn * S2);
            }
            xr[tl] = axr; xz[tl] = axz; xnw[tl] = axn;
#pragma unroll
            for (int r4 = 0; r4 < 4; ++r4) bhn[tl][r4] = bhh[128 + 16 * tt + 4 * g + r4] * S2;
        }
    };

    f32x4 hc[2] = {{0.f,0.f,0.f,0.f},{0.f,0.f,0.f,0.f}};
    bfrag hl = (bfrag){0,0,0,0,0,0,0,0};     // own k-tile h-frag (kt = w)
    bfrag ho = (bfrag){0,0,0,0,0,0,0,0};     // partner k-tile h-frag
    bfrag bx0 = (bfrag){0,0,0,0,0,0,0,0};    // ones row at k==8 -> g==2, e==0
    if (g == 2) bx0[0] = f2bf(1.f);

    // MFMA chains ordered x -> own-h -> partner-h so the barrier'd ds_read of ho
    // has ~6 MFMAs of slack before its first use.
    auto step = [&](const bfrag bx) {
#pragma unroll
        for (int tl = 0; tl < 2; ++tl) {
            f32x4 aIN = {0.f,0.f,0.f,0.f};
            aIN = MFMA16(xnw[tl], bx, aIN);
            f32x4 aR = {0.f,0.f,0.f,0.f};
            aR = MFMA16(xr[tl], bx, aR);
            aR = MFMA16(wr[tl][0], hl, aR);
            f32x4 aZ = {0.f,0.f,0.f,0.f};
            aZ = MFMA16(xz[tl], bx, aZ);
            aZ = MFMA16(wz[tl][0], hl, aZ);
            f32x4 aHN = bhn[tl];                      // bias via acc-init
            aHN = MFMA16(whn[tl][0], hl, aHN);
            aR  = MFMA16(wr[tl][1],  ho, aR);
            aZ  = MFMA16(wz[tl][1],  ho, aZ);
            aHN = MFMA16(whn[tl][1], ho, aHN);
#pragma unroll
            for (int r4 = 0; r4 < 4; ++r4) {
                // pre-activations arrive pre-scaled by log2e (r,z) / 2log2e (n)
                const float rg = __builtin_amdgcn_rcpf(1.f + __builtin_amdgcn_exp2f(-aR[r4]));
                const float zg = __builtin_amdgcn_rcpf(1.f + __builtin_amdgcn_exp2f(-aZ[r4]));
                const float np = aIN[r4] + rg * aHN[r4];
                const float ng = 1.f - 2.f * __builtin_amdgcn_rcpf(__builtin_amdgcn_exp2f(np) + 1.f);
                hc[tl][r4] = ng + zg * (hc[tl][r4] - ng);
            }
        }
        bfrag nl;
#pragma unroll
        for (int e = 0; e < 8; ++e) nl[e] = f2bf(hc[e >> 2][e & 3]);
        hl = nl;
    };

    auto make_bx = [&](const float4 xv) {
        bfrag bx = bx0;
        if (g < 2) { bx[0] = f2bf(xv.x); bx[1] = f2bf(xv.y); bx[2] = f2bf(xv.z); bx[3] = f2bf(xv.w); }
        return bx;
    };

    const unsigned istep = B_SIZE * F_DIM * 4;
    const unsigned off0  = ((unsigned)(blockIdx.x * 16 + c) * F_DIM + 4 * g) * 4;

    // ================= encoder =================
    load_phase(eWih, eWhh, ebih, ebhh);
    __syncthreads();
    float4 xn = make_float4(0.f, 0.f, 0.f, 0.f);
    if (g < 2) xn = ld4((const char*)inputs + off0);
    unsigned ioff = off0 + istep;

    auto enc_body = [&](const int P, const int t) {   // P = compile-time parity slot
        const float4 xv = xn;
        if (g < 2 && t + 1 < T_STEPS) xn = ld4((const char*)inputs + ioff);  // in flight across barrier
        ioff += istep;
        step(make_bx(xv));
        sEx[P][w][lane] = __builtin_bit_cast(u32x4, hl);
        LDS_BARRIER();
        ho = __builtin_bit_cast(bfrag, sEx[P][w ^ 1][lane]);
    };
#pragma unroll 1
    for (int t = 0; t < T_STEPS; t += 2) {
        enc_body(0, t);
        enc_body(1, t + 1);
    }

    // ================= decoder =================
    // (2-parity buffer + collective barriers make immediate sEx reuse safe)
    load_phase(dWih, dWhh, dbih, dbhh);   // pure register work, no LDS
    bfrag wo_own, wo_oth;   // out-proj A-frags: own k-tile (= hl), partner k-tile (= ho)
    f32x4 obv;
#pragma unroll
    for (int j = 0; j < 2; ++j) {
        bfrag f;
#pragma unroll
        for (int e = 0; e < 8; ++e) {
            const int k = 32 * ((j == 0) ? w : 1 - w) + 16 * (e >> 2) + 4 * g + (e & 3);
            f[e] = f2bf((c < F_DIM) ? oW[c * H_DIM + k] : 0.f);
        }
        if (j == 0) wo_own = f; else wo_oth = f;
    }
#pragma unroll
    for (int r4 = 0; r4 < 4; ++r4) obv[r4] = (g < 2) ? ob[4 * g + r4] : 0.f;

    unsigned toff = off0;           // target[t] feeds x_{t+1}
    unsigned ooff = off0;
    xn = make_float4(0.f, 0.f, 0.f, 0.f);   // teacher forcing: x_0 = 0

    auto dec_body = [&](const int P, const int t) {
        const float4 xv = xn;
        if (g < 2 && t + 1 < T_STEPS) xn = ld4((const char*)target + toff);
        toff += istep;
        step(make_bx(xv));
        sEx[P][w][lane] = __builtin_bit_cast(u32x4, hl);
        LDS_BARRIER();
        ho = __builtin_bit_cast(bfrag, sEx[P][w ^ 1][lane]);
        // out-projection alternates between the two waves by t-parity
        if (((t + w) & 1) == 0) {
            f32x4 aO = obv;
            aO = MFMA16(wo_own, hl, aO);
            aO = MFMA16(wo_oth, ho, aO);
            if (g < 2) {
                float4 o; o.x = aO[0]; o.y = aO[1]; o.z = aO[2]; o.w = aO[3];
                *(float4*)((char*)out + ooff) = o;
            }
        }
        ooff += istep;
    };
#pragma unroll 1
    for (int t = 0; t < T_STEPS; t += 2) {
        dec_body(0, t);
        dec_body(1, t + 1);
    }
}

extern "C" void kernel_launch(void* const* d_in, const int* in_sizes, int n_in,
                              void* d_out, int out_size, void* d_ws, size_t ws_size,
                              hipStream_t stream) {
    (void)in_sizes; (void)n_in; (void)d_ws; (void)ws_size; (void)out_size;
    const float* inputs = (const float*)d_in[0];
    const float* target = (const float*)d_in[1];
    const float* eWih   = (const float*)d_in[2];
    const float* eWhh   = (const float*)d_in[3];
    const float* ebih   = (const float*)d_in[4];
    const float* ebhh   = (const float*)d_in[5];
    const float* dWih   = (const float*)d_in[6];
    const float* dWhh   = (const float*)d_in[7];
    const float* dbih   = (const float*)d_in[8];
    const float* dbhh   = (const float*)d_in[9];
    const float* oW     = (const float*)d_in[10];
    const float* ob     = (const float*)d_in[11];
    float* out = (float*)d_out;

    seq2seq_r9_kernel<<<dim3(GRID_BLOCKS), dim3(BLOCK_THREADS), 0, stream>>>(
        inputs, target, eWih, eWhh, ebih, ebhh, dWih, dWhh, dbih, dbhh, oW, ob, out);
}

// Round 10
// 483.442 us; speedup vs baseline: 1.1059x; 1.1059x over previous
//
#include <hip/hip_runtime.h>

#define T_STEPS 128
#define B_SIZE  32768
#define F_DIM   8
#define H_DIM   64

#define BLOCK_THREADS 256                 // 4 waves; wave q owns h-units [16q,16q+16)
#define GRID_BLOCKS   (B_SIZE / 32)       // 1024 blocks x 2 groups of 16 samples

typedef float f32x4 __attribute__((ext_vector_type(4)));
typedef short bfrag __attribute__((ext_vector_type(8)));   // 8 bf16 (4 VGPRs)
typedef short s16x4 __attribute__((ext_vector_type(4)));
typedef unsigned int u32x2 __attribute__((ext_vector_type(2)));
typedef unsigned int u32x4 __attribute__((ext_vector_type(4)));

#define MFMA16(A, B, C) __builtin_amdgcn_mfma_f32_16x16x32_bf16((A), (B), (C), 0, 0, 0)

__device__ __forceinline__ short f2bf(float f) { return __builtin_bit_cast(short, (__bf16)f); }
__device__ __forceinline__ float4 ld4(const void* p) { return *(const float4*)p; }

constexpr float S1 = 1.4426950408889634f;  // log2(e)   -> folded into r,z weights
constexpr float S2 = 2.f * S1;             // 2*log2(e) -> folded into n weights

// Layout (verified rounds 2-9):
//  A/B frag elem e -> k = 32*kt + 16*(e>>2) + 4*g + (e&3); A row / B col = lane&15
//  C/D: col = lane&15 (sample), row = 4*g + reg
// 4-way h-split: wave q owns output rows [16q,16q+16) of each gate. Its hc[r4]
// maps to hB frag kt=q>>1, elems e=4*(q&1)+r4 -> one 8B half-fragment to exchange.
// Two independent 16-sample groups per block share the weight registers: 8
// recurrence chains per SIMD at 4 waves/SIMD, all blocks resident (no tail).
// Cap law (R2-R9): VGPR cap = 256/launch_bounds_w; w=2 -> 128 >= demand ~105.

__global__ void __launch_bounds__(BLOCK_THREADS, 2)
seq2seq_q4_kernel(const float* __restrict__ inputs, const float* __restrict__ target,
                  const float* __restrict__ eWih, const float* __restrict__ eWhh,
                  const float* __restrict__ ebih, const float* __restrict__ ebhh,
                  const float* __restrict__ dWih, const float* __restrict__ dWhh,
                  const float* __restrict__ dbih, const float* __restrict__ dbhh,
                  const float* __restrict__ oW, const float* __restrict__ ob,
                  float* __restrict__ out)
{
    __shared__ u32x2 sEx[2][2][2][64][2];   // [parity][grp][kt][lane][half] = 8 KB
    __shared__ u32x4 sWo[2][64];            // out-proj A-frags [kt][lane]     = 2 KB

    const int tid  = threadIdx.x;
    const int lane = tid & 63;
    const int q    = tid >> 6;        // wave id = owned tt
    const int c    = lane & 15;       // sample col / A row
    const int g    = lane >> 4;       // lane group
    const int kq   = q >> 1;          // own frag kt
    const int hq   = q & 1;           // own half within frag

    bfrag wr[2], wz[2], whn[2];       // h-side A-frags for own 16 rows, [kt]
    bfrag xr, xz, xnw;                // x-ktile A-frags (k<8 = Wih, k==8 = bias row)
    f32x4 bhn;                        // bhh n-rows (scaled) -> acc-init for aHN

    auto load_phase = [&](const float* __restrict__ Wih, const float* __restrict__ Whh,
                          const float* __restrict__ bih, const float* __restrict__ bhh) {
        const int rowR = 16 * q + c, rowZ = rowR + 64, rowN = rowR + 128;
#pragma unroll
        for (int kt = 0; kt < 2; ++kt) {
            bfrag fr, fz, fn;
#pragma unroll
            for (int e = 0; e < 8; ++e) {
                const int k = 32 * kt + 16 * (e >> 2) + 4 * g + (e & 3);
                fr[e] = f2bf(Whh[rowR * H_DIM + k] * S1);
                fz[e] = f2bf(Whh[rowZ * H_DIM + k] * S1);
                fn[e] = f2bf(Whh[rowN * H_DIM + k] * S2);
            }
            wr[kt] = fr; wz[kt] = fz; whn[kt] = fn;
        }
#pragma unroll
        for (int e = 0; e < 8; ++e) {
            const int k = 16 * (e >> 2) + 4 * g + (e & 3);
            float vr = 0.f, vz = 0.f, vn = 0.f;
            if (k < F_DIM) {
                vr = Wih[rowR * F_DIM + k]; vz = Wih[rowZ * F_DIM + k]; vn = Wih[rowN * F_DIM + k];
            } else if (k == F_DIM) {
                vr = bih[rowR] + bhh[rowR]; vz = bih[rowZ] + bhh[rowZ]; vn = bih[rowN];
            }
            xr[e] = f2bf(vr * S1); xz[e] = f2bf(vz * S1); xnw[e] = f2bf(vn * S2);
        }
#pragma unroll
        for (int r4 = 0; r4 < 4; ++r4) bhn[r4] = bhh[128 + 16 * q + 4 * g + r4] * S2;
    };

    f32x4 hc[2] = {{0.f,0.f,0.f,0.f},{0.f,0.f,0.f,0.f}};                 // [grp]
    bfrag hB[2][2] = {{(bfrag){0,0,0,0,0,0,0,0},(bfrag){0,0,0,0,0,0,0,0}},
                      {(bfrag){0,0,0,0,0,0,0,0},(bfrag){0,0,0,0,0,0,0,0}}};  // [grp][kt]
    bfrag bx0 = (bfrag){0,0,0,0,0,0,0,0};    // ones row at k==8 -> g==2, e==0
    if (g == 2) bx0[0] = f2bf(1.f);

    auto make_bx = [&](const float4 xv) {
        bfrag bx = bx0;
        if (g < 2) { bx[0] = f2bf(xv.x); bx[1] = f2bf(xv.y); bx[2] = f2bf(xv.z); bx[3] = f2bf(xv.w); }
        return bx;
    };

    // One group's GRU step: 9 MFMAs + epilogue; returns packed own 8B of h_new.
    auto step = [&](const bfrag bx, const bfrag hB0, const bfrag hB1, f32x4& HC) -> u32x2 {
        f32x4 aIN = {0.f,0.f,0.f,0.f};
        aIN = MFMA16(xnw, bx, aIN);
        f32x4 aR = {0.f,0.f,0.f,0.f};
        aR = MFMA16(xr, bx, aR);
        aR = MFMA16(wr[0], hB0, aR);
        aR = MFMA16(wr[1], hB1, aR);
        f32x4 aZ = {0.f,0.f,0.f,0.f};
        aZ = MFMA16(xz, bx, aZ);
        aZ = MFMA16(wz[0], hB0, aZ);
        aZ = MFMA16(wz[1], hB1, aZ);
        f32x4 aHN = bhn;                          // bias via acc-init
        aHN = MFMA16(whn[0], hB0, aHN);
        aHN = MFMA16(whn[1], hB1, aHN);
        s16x4 nb;
#pragma unroll
        for (int r4 = 0; r4 < 4; ++r4) {
            // pre-activations arrive pre-scaled by log2e (r,z) / 2log2e (n)
            const float rg = __builtin_amdgcn_rcpf(1.f + __builtin_amdgcn_exp2f(-aR[r4]));
            const float zg = __builtin_amdgcn_rcpf(1.f + __builtin_amdgcn_exp2f(-aZ[r4]));
            const float np = aIN[r4] + rg * aHN[r4];
            const float ng = 1.f - 2.f * __builtin_amdgcn_rcpf(__builtin_amdgcn_exp2f(np) + 1.f);
            HC[r4] = ng + zg * (HC[r4] - ng);
            nb[r4] = f2bf(HC[r4]);
        }
        return __builtin_bit_cast(u32x2, nb);
    };

    const unsigned istep = B_SIZE * F_DIM * 4;
    const unsigned offg[2] = {
        ((unsigned)(blockIdx.x * 32 + c) * F_DIM + 4 * g) * 4u,
        ((unsigned)(blockIdx.x * 32 + 16 + c) * F_DIM + 4 * g) * 4u };

    // ================= encoder =================
    load_phase(eWih, eWhh, ebih, ebhh);
    __syncthreads();
    float4 xn[2] = {make_float4(0.f,0.f,0.f,0.f), make_float4(0.f,0.f,0.f,0.f)};
    if (g < 2) { xn[0] = ld4((const char*)inputs + offg[0]); xn[1] = ld4((const char*)inputs + offg[1]); }
    unsigned ioff = istep;

    auto enc_body = [&](const int P, const int t) {   // P = compile-time parity slot
#pragma unroll
        for (int grp = 0; grp < 2; ++grp) {
            const float4 xv = xn[grp];
            if (g < 2 && t + 1 < T_STEPS) xn[grp] = ld4((const char*)inputs + ioff + offg[grp]);
            const u32x2 nl = step(make_bx(xv), hB[grp][0], hB[grp][1], hc[grp]);
            sEx[P][grp][kq][lane][hq] = nl;
        }
        ioff += istep;
        __syncthreads();                          // all 8 half-frags written
#pragma unroll
        for (int grp = 0; grp < 2; ++grp) {
            hB[grp][0] = __builtin_bit_cast(bfrag, *(const u32x4*)&sEx[P][grp][0][lane][0]);
            hB[grp][1] = __builtin_bit_cast(bfrag, *(const u32x4*)&sEx[P][grp][1][lane][0]);
        }
    };
#pragma unroll 1
    for (int t = 0; t < T_STEPS; t += 2) {
        enc_body(0, t);
        enc_body(1, t + 1);
    }

    // ================= decoder =================
    __syncthreads();   // encoder sEx readers done
    load_phase(dWih, dWhh, dbih, dbhh);
    if (q < 2) {       // wave q writes out-proj frag kt=q to LDS
        u32x4 f;
        bfrag bf_;
#pragma unroll
        for (int e = 0; e < 8; ++e) {
            const int k = 32 * q + 16 * (e >> 2) + 4 * g + (e & 3);
            bf_[e] = f2bf((c < F_DIM) ? oW[c * H_DIM + k] : 0.f);
        }
        f = __builtin_bit_cast(u32x4, bf_);
        sWo[q][lane] = f;
    }
    f32x4 obv;
#pragma unroll
    for (int r4 = 0; r4 < 4; ++r4) obv[r4] = (g < 2) ? ob[4 * g + r4] : 0.f;
    __syncthreads();

    unsigned toff = 0;              // target[t] feeds x_{t+1}
    unsigned ooff = 0;
    xn[0] = xn[1] = make_float4(0.f, 0.f, 0.f, 0.f);   // teacher forcing: x_0 = 0

    auto dec_body = [&](const int P, const int t) {
#pragma unroll
        for (int grp = 0; grp < 2; ++grp) {
            const float4 xv = xn[grp];
            if (g < 2 && t + 1 < T_STEPS) xn[grp] = ld4((const char*)target + toff + offg[grp]);
            const u32x2 nl = step(make_bx(xv), hB[grp][0], hB[grp][1], hc[grp]);
            sEx[P][grp][kq][lane][hq] = nl;
        }
        toff += istep;
        __syncthreads();
#pragma unroll
        for (int grp = 0; grp < 2; ++grp) {
            hB[grp][0] = __builtin_bit_cast(bfrag, *(const u32x4*)&sEx[P][grp][0][lane][0]);
            hB[grp][1] = __builtin_bit_cast(bfrag, *(const u32x4*)&sEx[P][grp][1][lane][0]);
        }
        // out-projection: rotating wave handles both groups this step
        if ((t & 3) == q) {
            const bfrag wo0 = __builtin_bit_cast(bfrag, sWo[0][lane]);
            const bfrag wo1 = __builtin_bit_cast(bfrag, sWo[1][lane]);
#pragma unroll
            for (int grp = 0; grp < 2; ++grp) {
                f32x4 aO = obv;
                aO = MFMA16(wo0, hB[grp][0], aO);
                aO = MFMA16(wo1, hB[grp][1], aO);
                if (g < 2) {
                    float4 o; o.x = aO[0]; o.y = aO[1]; o.z = aO[2]; o.w = aO[3];
                    *(float4*)((char*)out + ooff + offg[grp]) = o;
                }
            }
        }
        ooff += istep;
    };
#pragma unroll 1
    for (int t = 0; t < T_STEPS; t += 2) {
        dec_body(0, t);
        dec_body(1, t + 1);
    }
}

extern "C" void kernel_launch(void* const* d_in, const int* in_sizes, int n_in,
                              void* d_out, int out_size, void* d_ws, size_t ws_size,
                              hipStream_t stream) {
    (void)in_sizes; (void)n_in; (void)d_ws; (void)ws_size; (void)out_size;
    const float* inputs = (const float*)d_in[0];
    const float* target = (const float*)d_in[1];
    const float* eWih   = (const float*)d_in[2];
    const float* eWhh   = (const float*)d_in[3];
    const float* ebih   = (const float*)d_in[4];
    const float* ebhh   = (const float*)d_in[5];
    const float* dWih   = (const float*)d_in[6];
    const float* dWhh   = (const float*)d_in[7];
    const float* dbih   = (const float*)d_in[8];
    const float* dbhh   = (const float*)d_in[9];
    const float* oW     = (const float*)d_in[10];
    const float* ob     = (const float*)d_in[11];
    float* out = (float*)d_out;

    seq2seq_q4_kernel<<<dim3(GRID_BLOCKS), dim3(BLOCK_THREADS), 0, stream>>>(
        inputs, target, eWih, eWhh, ebih, ebhh, dWih, dWhh, dbih, dbhh, oW, ob, out);
}